// Round 1
// baseline (3065.723 us; speedup 1.0000x reference)
//
#include <hip/hip_runtime.h>
#include <math.h>

constexpr int NN = 50000;
constexpr int NE = 800000;

// ---------------- degree / dinv ----------------
__global__ void k_deg(const int* __restrict__ dst, float* __restrict__ deg) {
    int i = blockIdx.x * blockDim.x + threadIdx.x;
    if (i < NE) atomicAdd(&deg[dst[i]], 1.0f);
}

__global__ void k_dinv(float* __restrict__ deg) {
    int i = blockIdx.x * blockDim.x + threadIdx.x;
    if (i < NN) deg[i] = rsqrtf(fmaxf(deg[i], 1.0f));  // in-place: deg -> dinv
}

// ---------------- elementwise row-scale: S = H * dinv[row] ----------------
__global__ void k_scale(const float* __restrict__ H, const float* __restrict__ dinv,
                        float* __restrict__ S) {
    int idx = blockIdx.x * blockDim.x + threadIdx.x;  // float4 index, 128 cols -> 32/row
    if (idx < NN * 32) {
        int row = idx >> 5;
        float d = dinv[row];
        float4 v = reinterpret_cast<const float4*>(H)[idx];
        v.x *= d; v.y *= d; v.z *= d; v.w *= d;
        reinterpret_cast<float4*>(S)[idx] = v;
    }
}

// ---------------- edge scatter: AGG[dst] += S[src] ----------------
__global__ void k_scatter(const int* __restrict__ src, const int* __restrict__ dst,
                          const float* __restrict__ S, float* __restrict__ AGG) {
    int idx = blockIdx.x * blockDim.x + threadIdx.x;  // (edge, c4)
    int e = idx >> 5;
    if (e < NE) {
        int c = (idx & 31) * 4;
        int s = src[e], d = dst[e];
        float4 v = *reinterpret_cast<const float4*>(&S[(size_t)s * 128 + c]);
        float* p = &AGG[(size_t)d * 128 + c];
        atomicAdd(p + 0, v.x);
        atomicAdd(p + 1, v.y);
        atomicAdd(p + 2, v.z);
        atomicAdd(p + 3, v.w);
    }
}

// ---------------- combine: O = H + AGG * dinv[row] ----------------
__global__ void k_combine(const float* __restrict__ H, const float* __restrict__ AGG,
                          const float* __restrict__ dinv, float* __restrict__ O) {
    int idx = blockIdx.x * blockDim.x + threadIdx.x;
    if (idx < NN * 32) {
        int row = idx >> 5;
        float d = dinv[row];
        float4 h = reinterpret_cast<const float4*>(H)[idx];
        float4 a = reinterpret_cast<const float4*>(AGG)[idx];
        h.x = fmaf(a.x, d, h.x);
        h.y = fmaf(a.y, d, h.y);
        h.z = fmaf(a.z, d, h.z);
        h.w = fmaf(a.w, d, h.w);
        reinterpret_cast<float4*>(O)[idx] = h;
    }
}

// ---------------- column stats for BN: sum, sumsq over 256 cols ----------------
__global__ void k_colstats(const float* __restrict__ Z, float* __restrict__ stats) {
    int c = threadIdx.x;  // 256 threads = 256 cols
    int rows_per_block = (NN + gridDim.x - 1) / gridDim.x;
    int r0 = blockIdx.x * rows_per_block;
    int r1 = min(r0 + rows_per_block, NN);
    float s = 0.f, s2 = 0.f;
    for (int r = r0; r < r1; ++r) {
        float z = Z[(size_t)r * 256 + c];
        s += z;
        s2 = fmaf(z, z, s2);
    }
    atomicAdd(&stats[c], s);
    atomicAdd(&stats[256 + c], s2);
}

// ---------------- tiled fp32 GEMM: C[M,NCOLS] = op(A[M,K]) @ B[K,NCOLS] (+bias) ----------------
// BNRELU: A element at column k transformed by relu((a-mu[k])*rsqrt(var[k]+eps)*gamma[k]+beta[k])
template <int K, int NCOLS, bool BIAS, bool BNRELU>
__global__ __launch_bounds__(256) void k_gemm(
    const float* __restrict__ A, const float* __restrict__ B,
    const float* __restrict__ bias, const float* __restrict__ stats,
    const float* __restrict__ gamma, const float* __restrict__ beta,
    float* __restrict__ C, int M)
{
    constexpr int BM = 64, BN = 128, BK = 16;
    __shared__ __align__(16) float As[BK][BM + 4];  // stride 68 floats (272B, 16B-aligned)
    __shared__ __align__(16) float Bs[BK][BN];

    const int tid = threadIdx.x;
    const int tx = tid & 15;   // 0..15, 8 cols each
    const int ty = tid >> 4;   // 0..15, 4 rows each
    const int row0 = blockIdx.x * BM;
    const int col0 = blockIdx.y * BN;

    float acc[4][8];
#pragma unroll
    for (int i = 0; i < 4; ++i)
#pragma unroll
        for (int j = 0; j < 8; ++j) acc[i][j] = 0.f;

    const int aRow = tid >> 2;        // 0..63
    const int aK4  = (tid & 3) * 4;   // 0,4,8,12
    const int bR   = tid >> 5;        // 0..7
    const int bC   = (tid & 31) * 4;  // 0..124

    for (int k0 = 0; k0 < K; k0 += BK) {
        // ---- stage A tile (transposed into As[k][m]) ----
        float4 av;
        if (row0 + aRow < M) {
            av = *reinterpret_cast<const float4*>(&A[(size_t)(row0 + aRow) * K + k0 + aK4]);
        } else {
            av = make_float4(0.f, 0.f, 0.f, 0.f);
        }
        if constexpr (BNRELU) {
            float vv[4] = {av.x, av.y, av.z, av.w};
#pragma unroll
            for (int q = 0; q < 4; ++q) {
                int kcol = k0 + aK4 + q;
                float mu  = stats[kcol] * (1.0f / NN);
                float var = stats[256 + kcol] * (1.0f / NN) - mu * mu;
                float inv = rsqrtf(var + 1e-5f);
                vv[q] = fmaxf(fmaf((vv[q] - mu) * inv, gamma[kcol], beta[kcol]), 0.f);
            }
            av.x = vv[0]; av.y = vv[1]; av.z = vv[2]; av.w = vv[3];
        }
        As[aK4 + 0][aRow] = av.x;
        As[aK4 + 1][aRow] = av.y;
        As[aK4 + 2][aRow] = av.z;
        As[aK4 + 3][aRow] = av.w;

        // ---- stage B tile ----
#pragma unroll
        for (int rr = 0; rr < 2; ++rr) {
            int kk = bR + rr * 8;
            float4 bv = *reinterpret_cast<const float4*>(&B[(size_t)(k0 + kk) * NCOLS + col0 + bC]);
            *reinterpret_cast<float4*>(&Bs[kk][bC]) = bv;
        }
        __syncthreads();

#pragma unroll
        for (int kk = 0; kk < BK; ++kk) {
            float4 a  = *reinterpret_cast<const float4*>(&As[kk][ty * 4]);
            float4 b0 = *reinterpret_cast<const float4*>(&Bs[kk][tx * 8]);
            float4 b1 = *reinterpret_cast<const float4*>(&Bs[kk][tx * 8 + 4]);
            float ar[4] = {a.x, a.y, a.z, a.w};
            float br[8] = {b0.x, b0.y, b0.z, b0.w, b1.x, b1.y, b1.z, b1.w};
#pragma unroll
            for (int i = 0; i < 4; ++i)
#pragma unroll
                for (int j = 0; j < 8; ++j)
                    acc[i][j] = fmaf(ar[i], br[j], acc[i][j]);
        }
        __syncthreads();
    }

#pragma unroll
    for (int i = 0; i < 4; ++i) {
        int r = row0 + ty * 4 + i;
        if (r < M) {
            float out[8];
#pragma unroll
            for (int j = 0; j < 8; ++j) {
                out[j] = acc[i][j];
                if constexpr (BIAS) out[j] += bias[col0 + tx * 8 + j];
            }
            float4* p = reinterpret_cast<float4*>(&C[(size_t)r * NCOLS + col0 + tx * 8]);
            p[0] = make_float4(out[0], out[1], out[2], out[3]);
            p[1] = make_float4(out[4], out[5], out[6], out[7]);
        }
    }
}

extern "C" void kernel_launch(void* const* d_in, const int* in_sizes, int n_in,
                              void* d_out, int out_size, void* d_ws, size_t ws_size,
                              hipStream_t stream) {
    const float* feat  = (const float*)d_in[0];
    const int*   src   = (const int*)d_in[1];
    const int*   dst   = (const int*)d_in[2];
    const float* W0    = (const float*)d_in[3];
    const float* W1    = (const float*)d_in[4];
    const float* Wp1   = (const float*)d_in[5];
    const float* bp1   = (const float*)d_in[6];
    const float* gamma = (const float*)d_in[7];
    const float* beta  = (const float*)d_in[8];
    const float* Wp2   = (const float*)d_in[9];
    const float* bp2   = (const float*)d_in[10];
    float* out = (float*)d_out;

    float* ws = (float*)d_ws;
    float* dinv  = ws;                       // NN floats (deg -> dinv in-place)
    float* bufA  = ws + 50000;               // NN*128
    float* bufB  = ws + 6450000;             // NN*128
    float* bufC  = ws + 12850000;            // NN*128 (AGG)
    float* Z     = ws + 19250000;            // NN*256
    float* stats = ws + 32050000;            // 512

    const int EW_BLK = (NN * 32 + 255) / 256;      // elementwise float4 grid
    const int GX = (NN + 63) / 64;                 // GEMM row tiles

    // degree -> dinv
    hipMemsetAsync(dinv, 0, NN * sizeof(float), stream);
    k_deg<<<(NE + 255) / 256, 256, 0, stream>>>(dst, dinv);
    k_dinv<<<(NN + 255) / 256, 256, 0, stream>>>(dinv);

    // H0 = feat @ W0
    k_gemm<512, 128, false, false><<<dim3(GX, 1), 256, 0, stream>>>(
        feat, W0, nullptr, nullptr, nullptr, nullptr, bufA, NN);

    // low_conv #1: bufB = H0*dinv; AGG; bufB(H1) = H0 + AGG*dinv
    k_scale<<<EW_BLK, 256, 0, stream>>>(bufA, dinv, bufB);
    hipMemsetAsync(bufC, 0, (size_t)NN * 128 * sizeof(float), stream);
    k_scatter<<<(NE * 32 + 255) / 256, 256, 0, stream>>>(src, dst, bufB, bufC);
    k_combine<<<EW_BLK, 256, 0, stream>>>(bufA, bufC, dinv, bufB);

    // H2 = H1 @ W1
    k_gemm<128, 128, false, false><<<dim3(GX, 1), 256, 0, stream>>>(
        bufB, W1, nullptr, nullptr, nullptr, nullptr, bufA, NN);

    // low_conv #2: bufB = H2*dinv; AGG; bufB(H3) = H2 + AGG*dinv
    k_scale<<<EW_BLK, 256, 0, stream>>>(bufA, dinv, bufB);
    hipMemsetAsync(bufC, 0, (size_t)NN * 128 * sizeof(float), stream);
    k_scatter<<<(NE * 32 + 255) / 256, 256, 0, stream>>>(src, dst, bufB, bufC);
    k_combine<<<EW_BLK, 256, 0, stream>>>(bufA, bufC, dinv, bufB);

    // Z = H3 @ Wp1 + bp1   [NN, 256]
    k_gemm<128, 256, true, false><<<dim3(GX, 2), 256, 0, stream>>>(
        bufB, Wp1, bp1, nullptr, nullptr, nullptr, Z, NN);

    // BN column stats
    hipMemsetAsync(stats, 0, 512 * sizeof(float), stream);
    k_colstats<<<500, 256, 0, stream>>>(Z, stats);

    // out = relu(BN(Z)) @ Wp2 + bp2
    k_gemm<256, 128, true, true><<<dim3(GX, 1), 256, 0, stream>>>(
        Z, Wp2, bp2, stats, gamma, beta, out, NN);
}

// Round 2
// 561.948 us; speedup vs baseline: 5.4555x; 5.4555x over previous
//
#include <hip/hip_runtime.h>
#include <math.h>

constexpr int NN = 50000;
constexpr int NE = 800000;
constexpr int NB = (NN + 255) / 256;   // 196 scan blocks

// ---------------- histogram of dst (int counts) ----------------
__global__ void k_count(const int* __restrict__ dst, int* __restrict__ cnt) {
    int i = blockIdx.x * blockDim.x + threadIdx.x;
    if (i < NE) atomicAdd(&cnt[dst[i]], 1);
}

__global__ void k_dinv(const int* __restrict__ cnt, float* __restrict__ dinv) {
    int i = blockIdx.x * blockDim.x + threadIdx.x;
    if (i < NN) dinv[i] = rsqrtf(fmaxf((float)cnt[i], 1.0f));
}

// ---------------- hierarchical exclusive scan of cnt -> rowoff ----------------
__global__ void k_bsum(const int* __restrict__ cnt, int* __restrict__ bsum) {
    int i = blockIdx.x * 256 + threadIdx.x;
    int v = (i < NN) ? cnt[i] : 0;
#pragma unroll
    for (int off = 32; off; off >>= 1) v += __shfl_down(v, off, 64);
    __shared__ int tmp[4];
    if ((threadIdx.x & 63) == 0) tmp[threadIdx.x >> 6] = v;
    __syncthreads();
    if (threadIdx.x == 0) bsum[blockIdx.x] = tmp[0] + tmp[1] + tmp[2] + tmp[3];
}

__global__ void k_scan_bsum(const int* __restrict__ bsum, int* __restrict__ boff) {
    __shared__ int s[256];
    int t = threadIdx.x;
    int v = (t < NB) ? bsum[t] : 0;
    s[t] = v;
    __syncthreads();
    for (int off = 1; off < 256; off <<= 1) {
        int u = (t >= off) ? s[t - off] : 0;
        __syncthreads();
        s[t] += u;
        __syncthreads();
    }
    if (t < NB) boff[t] = s[t] - v;  // exclusive
}

__global__ void k_scan_block(const int* __restrict__ cnt, const int* __restrict__ boff,
                             int* __restrict__ rowoff) {
    __shared__ int s[256];
    int t = threadIdx.x;
    int i = blockIdx.x * 256 + t;
    int v = (i < NN) ? cnt[i] : 0;
    s[t] = v;
    __syncthreads();
    for (int off = 1; off < 256; off <<= 1) {
        int u = (t >= off) ? s[t - off] : 0;
        __syncthreads();
        s[t] += u;
        __syncthreads();
    }
    if (i < NN) rowoff[i] = boff[blockIdx.x] + s[t] - v;  // exclusive
}

// ---------------- CSR fill: eidx[rowoff[d] + pos] = src ----------------
__global__ void k_fill(const int* __restrict__ src, const int* __restrict__ dst,
                       const int* __restrict__ rowoff, int* __restrict__ cursor,
                       int* __restrict__ eidx) {
    int e = blockIdx.x * blockDim.x + threadIdx.x;
    if (e < NE) {
        int d = dst[e];
        int p = atomicAdd(&cursor[d], 1);
        eidx[rowoff[d] + p] = src[e];
    }
}

// ---------------- fused low_conv gather: O = H + dinv * sum_e H[src]*dinv[src] ----------------
// one wave per node; each lane owns 2 of the 128 columns
__global__ __launch_bounds__(256) void k_gather(
    const float* __restrict__ H, const float* __restrict__ dinv,
    const int* __restrict__ rowoff, const int* __restrict__ cnt,
    const int* __restrict__ eidx, float* __restrict__ O)
{
    int node = blockIdx.x * 4 + (threadIdx.x >> 6);
    int lane = threadIdx.x & 63;
    if (node >= NN) return;
    int beg = rowoff[node];
    int n = cnt[node];
    float2 acc = make_float2(0.f, 0.f);
    for (int j = 0; j < n; ++j) {
        int s = eidx[beg + j];
        float ds = dinv[s];
        float2 v = *reinterpret_cast<const float2*>(&H[(size_t)s * 128 + lane * 2]);
        acc.x = fmaf(v.x, ds, acc.x);
        acc.y = fmaf(v.y, ds, acc.y);
    }
    float d = dinv[node];
    float2 h = *reinterpret_cast<const float2*>(&H[(size_t)node * 128 + lane * 2]);
    h.x = fmaf(acc.x, d, h.x);
    h.y = fmaf(acc.y, d, h.y);
    *reinterpret_cast<float2*>(&O[(size_t)node * 128 + lane * 2]) = h;
}

// ---------------- column stats for BN: sum, sumsq over 256 cols ----------------
__global__ void k_colstats(const float* __restrict__ Z, float* __restrict__ stats) {
    int c = threadIdx.x;  // 256 threads = 256 cols
    int rows_per_block = (NN + gridDim.x - 1) / gridDim.x;
    int r0 = blockIdx.x * rows_per_block;
    int r1 = min(r0 + rows_per_block, NN);
    float s = 0.f, s2 = 0.f;
    for (int r = r0; r < r1; ++r) {
        float z = Z[(size_t)r * 256 + c];
        s += z;
        s2 = fmaf(z, z, s2);
    }
    atomicAdd(&stats[c], s);
    atomicAdd(&stats[256 + c], s2);
}

// ---------------- tiled fp32 GEMM: C[M,NCOLS] = op(A[M,K]) @ B[K,NCOLS] (+bias) ----------------
template <int K, int NCOLS, bool BIAS, bool BNRELU>
__global__ __launch_bounds__(256) void k_gemm(
    const float* __restrict__ A, const float* __restrict__ B,
    const float* __restrict__ bias, const float* __restrict__ stats,
    const float* __restrict__ gamma, const float* __restrict__ beta,
    float* __restrict__ C, int M)
{
    constexpr int BM = 64, BN = 128, BK = 16;
    __shared__ __align__(16) float As[BK][BM + 4];
    __shared__ __align__(16) float Bs[BK][BN];

    const int tid = threadIdx.x;
    const int tx = tid & 15;   // 8 cols each
    const int ty = tid >> 4;   // 4 rows each
    const int row0 = blockIdx.x * BM;
    const int col0 = blockIdx.y * BN;

    float acc[4][8];
#pragma unroll
    for (int i = 0; i < 4; ++i)
#pragma unroll
        for (int j = 0; j < 8; ++j) acc[i][j] = 0.f;

    const int aRow = tid >> 2;
    const int aK4  = (tid & 3) * 4;
    const int bR   = tid >> 5;
    const int bC   = (tid & 31) * 4;

    for (int k0 = 0; k0 < K; k0 += BK) {
        float4 av;
        if (row0 + aRow < M) {
            av = *reinterpret_cast<const float4*>(&A[(size_t)(row0 + aRow) * K + k0 + aK4]);
        } else {
            av = make_float4(0.f, 0.f, 0.f, 0.f);
        }
        if constexpr (BNRELU) {
            float vv[4] = {av.x, av.y, av.z, av.w};
#pragma unroll
            for (int q = 0; q < 4; ++q) {
                int kcol = k0 + aK4 + q;
                float mu  = stats[kcol] * (1.0f / NN);
                float var = stats[256 + kcol] * (1.0f / NN) - mu * mu;
                float inv = rsqrtf(var + 1e-5f);
                vv[q] = fmaxf(fmaf((vv[q] - mu) * inv, gamma[kcol], beta[kcol]), 0.f);
            }
            av.x = vv[0]; av.y = vv[1]; av.z = vv[2]; av.w = vv[3];
        }
        As[aK4 + 0][aRow] = av.x;
        As[aK4 + 1][aRow] = av.y;
        As[aK4 + 2][aRow] = av.z;
        As[aK4 + 3][aRow] = av.w;

#pragma unroll
        for (int rr = 0; rr < 2; ++rr) {
            int kk = bR + rr * 8;
            float4 bv = *reinterpret_cast<const float4*>(&B[(size_t)(k0 + kk) * NCOLS + col0 + bC]);
            *reinterpret_cast<float4*>(&Bs[kk][bC]) = bv;
        }
        __syncthreads();

#pragma unroll
        for (int kk = 0; kk < BK; ++kk) {
            float4 a  = *reinterpret_cast<const float4*>(&As[kk][ty * 4]);
            float4 b0 = *reinterpret_cast<const float4*>(&Bs[kk][tx * 8]);
            float4 b1 = *reinterpret_cast<const float4*>(&Bs[kk][tx * 8 + 4]);
            float ar[4] = {a.x, a.y, a.z, a.w};
            float br[8] = {b0.x, b0.y, b0.z, b0.w, b1.x, b1.y, b1.z, b1.w};
#pragma unroll
            for (int i = 0; i < 4; ++i)
#pragma unroll
                for (int j = 0; j < 8; ++j)
                    acc[i][j] = fmaf(ar[i], br[j], acc[i][j]);
        }
        __syncthreads();
    }

#pragma unroll
    for (int i = 0; i < 4; ++i) {
        int r = row0 + ty * 4 + i;
        if (r < M) {
            float out[8];
#pragma unroll
            for (int j = 0; j < 8; ++j) {
                out[j] = acc[i][j];
                if constexpr (BIAS) out[j] += bias[col0 + tx * 8 + j];
            }
            float4* p = reinterpret_cast<float4*>(&C[(size_t)r * NCOLS + col0 + tx * 8]);
            p[0] = make_float4(out[0], out[1], out[2], out[3]);
            p[1] = make_float4(out[4], out[5], out[6], out[7]);
        }
    }
}

extern "C" void kernel_launch(void* const* d_in, const int* in_sizes, int n_in,
                              void* d_out, int out_size, void* d_ws, size_t ws_size,
                              hipStream_t stream) {
    const float* feat  = (const float*)d_in[0];
    const int*   src   = (const int*)d_in[1];
    const int*   dst   = (const int*)d_in[2];
    const float* W0    = (const float*)d_in[3];
    const float* W1    = (const float*)d_in[4];
    const float* Wp1   = (const float*)d_in[5];
    const float* bp1   = (const float*)d_in[6];
    const float* gamma = (const float*)d_in[7];
    const float* beta  = (const float*)d_in[8];
    const float* Wp2   = (const float*)d_in[9];
    const float* bp2   = (const float*)d_in[10];
    float* out = (float*)d_out;

    // workspace layout (floats/ints, 4B units)
    char* wsb = (char*)d_ws;
    float* dinv   = (float*)(wsb);                    // NN
    int*   cnt    = (int*)(wsb + 4u * 50048);         // NN
    int*   rowoff = (int*)(wsb + 4u * 100096);        // NN
    int*   cursor = (int*)(wsb + 4u * 150144);        // NN
    int*   bsum   = (int*)(wsb + 4u * 200192);        // 256
    int*   boff   = (int*)(wsb + 4u * 200448);        // 256
    int*   eidx   = (int*)(wsb + 4u * 200704);        // NE
    float* bufA   = (float*)(wsb + 4u * 1000704);     // NN*128
    float* bufB   = (float*)(wsb + 4u * 7400704);     // NN*128
    float* Z      = (float*)(wsb + 4u * 13800704);    // NN*256
    float* stats  = (float*)(wsb + 4u * 26600704);    // 512

    const int GX = (NN + 63) / 64;

    // ---- CSR build (once; shared by both convs) ----
    hipMemsetAsync(cnt, 0, NN * sizeof(int), stream);
    hipMemsetAsync(cursor, 0, NN * sizeof(int), stream);
    k_count<<<(NE + 255) / 256, 256, 0, stream>>>(dst, cnt);
    k_dinv<<<(NN + 255) / 256, 256, 0, stream>>>(cnt, dinv);
    k_bsum<<<NB, 256, 0, stream>>>(cnt, bsum);
    k_scan_bsum<<<1, 256, 0, stream>>>(bsum, boff);
    k_scan_block<<<NB, 256, 0, stream>>>(cnt, boff, rowoff);
    k_fill<<<(NE + 255) / 256, 256, 0, stream>>>(src, dst, rowoff, cursor, eidx);

    // H0 = feat @ W0
    k_gemm<512, 128, false, false><<<dim3(GX, 1), 256, 0, stream>>>(
        feat, W0, nullptr, nullptr, nullptr, nullptr, bufA, NN);

    // low_conv #1 (fused gather)
    k_gather<<<(NN + 3) / 4, 256, 0, stream>>>(bufA, dinv, rowoff, cnt, eidx, bufB);

    // H2 = H1 @ W1
    k_gemm<128, 128, false, false><<<dim3(GX, 1), 256, 0, stream>>>(
        bufB, W1, nullptr, nullptr, nullptr, nullptr, bufA, NN);

    // low_conv #2 (fused gather)
    k_gather<<<(NN + 3) / 4, 256, 0, stream>>>(bufA, dinv, rowoff, cnt, eidx, bufB);

    // Z = H3 @ Wp1 + bp1   [NN, 256]
    k_gemm<128, 256, true, false><<<dim3(GX, 2), 256, 0, stream>>>(
        bufB, Wp1, bp1, nullptr, nullptr, nullptr, Z, NN);

    // BN column stats
    hipMemsetAsync(stats, 0, 512 * sizeof(float), stream);
    k_colstats<<<500, 256, 0, stream>>>(Z, stats);

    // out = relu(BN(Z)) @ Wp2 + bp2
    k_gemm<256, 128, true, true><<<dim3(GX, 1), 256, 0, stream>>>(
        Z, Wp2, bp2, stats, gamma, beta, out, NN);
}

// Round 3
// 437.733 us; speedup vs baseline: 7.0036x; 1.2838x over previous
//
#include <hip/hip_runtime.h>
#include <math.h>

constexpr int NN  = 50000;
constexpr int NE  = 800000;
constexpr int NNP = 50048;             // padded rows = 391 * 128
constexpr int NB  = (NN + 255) / 256;  // scan blocks

typedef __bf16 bf16x8 __attribute__((ext_vector_type(8)));
typedef float  f32x4  __attribute__((ext_vector_type(4)));
typedef __attribute__((address_space(1))) unsigned int as1_uint;
typedef __attribute__((address_space(3))) unsigned int as3_uint;

__device__ __forceinline__ unsigned short f2bf(float x) {  // RNE fp32->bf16 bits
    unsigned int u = __float_as_uint(x);
    return (unsigned short)((u + 0x7FFFu + ((u >> 16) & 1u)) >> 16);
}
__device__ __forceinline__ float bf2f(unsigned short h) {
    return __uint_as_float(((unsigned int)h) << 16);
}

__device__ __forceinline__ void gload16(const unsigned short* g, unsigned short* l) {
    // direct global->LDS, 16B per lane (dest = wave-uniform base + lane*16)
    __builtin_amdgcn_global_load_lds((const as1_uint*)(unsigned long long)g,
                                     (as3_uint*)(unsigned long long)l, 16, 0, 0);
}

// ---------------- CSR build ----------------
__global__ void k_count(const int* __restrict__ dst, int* __restrict__ cnt) {
    int i = blockIdx.x * blockDim.x + threadIdx.x;
    if (i < NE) atomicAdd(&cnt[dst[i]], 1);
}

__global__ void k_dinv(const int* __restrict__ cnt, float* __restrict__ dinv) {
    int i = blockIdx.x * blockDim.x + threadIdx.x;
    if (i < NN) dinv[i] = rsqrtf(fmaxf((float)cnt[i], 1.0f));
}

__global__ void k_bsum(const int* __restrict__ cnt, int* __restrict__ bsum) {
    int i = blockIdx.x * 256 + threadIdx.x;
    int v = (i < NN) ? cnt[i] : 0;
#pragma unroll
    for (int off = 32; off; off >>= 1) v += __shfl_down(v, off, 64);
    __shared__ int tmp[4];
    if ((threadIdx.x & 63) == 0) tmp[threadIdx.x >> 6] = v;
    __syncthreads();
    if (threadIdx.x == 0) bsum[blockIdx.x] = tmp[0] + tmp[1] + tmp[2] + tmp[3];
}

__global__ void k_scan_bsum(const int* __restrict__ bsum, int* __restrict__ boff) {
    __shared__ int s[256];
    int t = threadIdx.x;
    int v = (t < NB) ? bsum[t] : 0;
    s[t] = v;
    __syncthreads();
    for (int off = 1; off < 256; off <<= 1) {
        int u = (t >= off) ? s[t - off] : 0;
        __syncthreads();
        s[t] += u;
        __syncthreads();
    }
    if (t < NB) boff[t] = s[t] - v;
}

__global__ void k_scan_block(const int* __restrict__ cnt, const int* __restrict__ boff,
                             int* __restrict__ rowoff) {
    __shared__ int s[256];
    int t = threadIdx.x;
    int i = blockIdx.x * 256 + t;
    int v = (i < NN) ? cnt[i] : 0;
    s[t] = v;
    __syncthreads();
    for (int off = 1; off < 256; off <<= 1) {
        int u = (t >= off) ? s[t - off] : 0;
        __syncthreads();
        s[t] += u;
        __syncthreads();
    }
    if (i < NN) rowoff[i] = boff[blockIdx.x] + s[t] - v;
}

__global__ void k_fill(const int* __restrict__ src, const int* __restrict__ dst,
                       const int* __restrict__ rowoff, int* __restrict__ cursor,
                       int* __restrict__ eidx) {
    int e = blockIdx.x * blockDim.x + threadIdx.x;
    if (e < NE) {
        int d = dst[e];
        int p = atomicAdd(&cursor[d], 1);
        eidx[rowoff[d] + p] = src[e];
    }
}

// ---------------- fused low_conv gather, emitting hi/lo bf16 split ----------------
__global__ __launch_bounds__(256) void k_gather_split(
    const float* __restrict__ H, const float* __restrict__ dinv,
    const int* __restrict__ rowoff, const int* __restrict__ cnt,
    const int* __restrict__ eidx, unsigned short* __restrict__ OH,
    unsigned short* __restrict__ OL)
{
    int node = blockIdx.x * 4 + (threadIdx.x >> 6);
    int lane = threadIdx.x & 63;
    if (node >= NNP) return;
    size_t o = (size_t)node * 128 + lane * 2;
    if (node >= NN) {  // zero the pad rows
        *reinterpret_cast<ushort2*>(&OH[o]) = make_ushort2(0, 0);
        *reinterpret_cast<ushort2*>(&OL[o]) = make_ushort2(0, 0);
        return;
    }
    int beg = rowoff[node];
    int n = cnt[node];
    float2 acc = make_float2(0.f, 0.f);
    for (int j = 0; j < n; ++j) {
        int s = eidx[beg + j];
        float ds = dinv[s];
        float2 v = *reinterpret_cast<const float2*>(&H[(size_t)s * 128 + lane * 2]);
        acc.x = fmaf(v.x, ds, acc.x);
        acc.y = fmaf(v.y, ds, acc.y);
    }
    float d = dinv[node];
    float2 h = *reinterpret_cast<const float2*>(&H[(size_t)node * 128 + lane * 2]);
    h.x = fmaf(acc.x, d, h.x);
    h.y = fmaf(acc.y, d, h.y);
    ushort2 hv, lv;
    hv.x = f2bf(h.x); lv.x = f2bf(h.x - bf2f(hv.x));
    hv.y = f2bf(h.y); lv.y = f2bf(h.y - bf2f(hv.y));
    *reinterpret_cast<ushort2*>(&OH[o]) = hv;
    *reinterpret_cast<ushort2*>(&OL[o]) = lv;
}

// ---------------- converters ----------------
__global__ void k_feat_bf16(const float* __restrict__ F, unsigned short* __restrict__ FH) {
    int idx = blockIdx.x * blockDim.x + threadIdx.x;  // float4 over [NNP][512]
    if (idx >= NNP * 128) return;
    int row = idx >> 7;
    ushort4 o;
    if (row < NN) {
        float4 v = reinterpret_cast<const float4*>(F)[idx];
        o = make_ushort4(f2bf(v.x), f2bf(v.y), f2bf(v.z), f2bf(v.w));
    } else o = make_ushort4(0, 0, 0, 0);
    reinterpret_cast<ushort4*>(FH)[idx] = o;
}

__global__ void k_wsplit(const float* __restrict__ W, unsigned short* __restrict__ th,
                         unsigned short* __restrict__ tl, int K, int N) {
    int idx = blockIdx.x * blockDim.x + threadIdx.x;  // W[K][N] -> Wt[N][K] hi/lo
    if (idx < K * N) {
        int k = idx / N, n = idx - k * N;
        float a = W[idx];
        unsigned short hi = f2bf(a);
        float lo = a - bf2f(hi);
        th[(size_t)n * K + k] = hi;
        tl[(size_t)n * K + k] = f2bf(lo);
    }
}

// ---------------- BN stats / prep / apply ----------------
__global__ void k_colstats(const float* __restrict__ Z, float* __restrict__ stats) {
    int c = threadIdx.x;
    int rows_per_block = (NN + gridDim.x - 1) / gridDim.x;
    int r0 = blockIdx.x * rows_per_block;
    int r1 = min(r0 + rows_per_block, NN);
    float s = 0.f, s2 = 0.f;
    for (int r = r0; r < r1; ++r) {
        float z = Z[(size_t)r * 256 + c];
        s += z;
        s2 = fmaf(z, z, s2);
    }
    atomicAdd(&stats[c], s);
    atomicAdd(&stats[256 + c], s2);
}

__global__ void k_bnprep(const float* __restrict__ stats, const float* __restrict__ gamma,
                         const float* __restrict__ beta, float* __restrict__ scale,
                         float* __restrict__ shift) {
    int c = threadIdx.x;  // 256
    float mu  = stats[c] * (1.0f / NN);
    float var = stats[256 + c] * (1.0f / NN) - mu * mu;
    float s = gamma[c] * rsqrtf(var + 1e-5f);
    scale[c] = s;
    shift[c] = beta[c] - mu * s;
}

__global__ void k_bnbf16(const float* __restrict__ Z, const float* __restrict__ scale,
                         const float* __restrict__ shift, unsigned short* __restrict__ OH) {
    int idx = blockIdx.x * blockDim.x + threadIdx.x;  // float4 over [NNP][256]
    if (idx >= NNP * 64) return;
    int row = idx >> 6;
    int c4 = (idx & 63) * 4;
    ushort4 o;
    if (row < NN) {
        float4 z = reinterpret_cast<const float4*>(Z)[idx];
        float v0 = fmaxf(fmaf(z.x, scale[c4 + 0], shift[c4 + 0]), 0.f);
        float v1 = fmaxf(fmaf(z.y, scale[c4 + 1], shift[c4 + 1]), 0.f);
        float v2 = fmaxf(fmaf(z.z, scale[c4 + 2], shift[c4 + 2]), 0.f);
        float v3 = fmaxf(fmaf(z.w, scale[c4 + 3], shift[c4 + 3]), 0.f);
        o = make_ushort4(f2bf(v0), f2bf(v1), f2bf(v2), f2bf(v3));
    } else o = make_ushort4(0, 0, 0, 0);
    reinterpret_cast<ushort4*>(OH)[idx] = o;
}

// ---------------- split-precision MFMA GEMM ----------------
// C[M,NCOLS](fp32) = (AH + AL) @ (BH + BL)^T-stored, A:[NNP][K] bf16, Bt:[NCOLS][K] bf16.
// 128x128 tile, BK=32, 8 waves (wave tile 32x64). XOR swizzle on k-group vs row:
// LDS linear dest (global_load_lds), inverse-swizzled global source, swizzled frag read.
template <int K, int NCOLS, bool BIAS, bool ALO>
__global__ __launch_bounds__(512) void k_mfma(
    const unsigned short* __restrict__ AH, const unsigned short* __restrict__ AL,
    const unsigned short* __restrict__ BH, const unsigned short* __restrict__ BL,
    const float* __restrict__ bias, float* __restrict__ C)
{
    __shared__ __align__(16) unsigned short lds[4 * 4096];  // Ahi, Alo, Bhi, Blo (8KB each)
    unsigned short* ldsAH = lds;
    unsigned short* ldsAL = lds + 4096;
    unsigned short* ldsBH = lds + 8192;
    unsigned short* ldsBL = lds + 12288;

    const int tid  = threadIdx.x;
    const int lane = tid & 63;
    const int wid  = tid >> 6;       // 0..7
    const int wm   = wid >> 1;       // 0..3  (rows wm*32)
    const int wn   = wid & 1;        // 0..1  (cols wn*64)
    const int row0 = blockIdx.x * 128;
    const int col0 = blockIdx.y * 128;

    // staging: thread tid owns LDS chunk tid (16B) of each buffer
    const int srow  = tid >> 2;                    // 0..127 (tile row / tile col)
    const int skg   = tid & 3;                     // 16B k-group within row
    const int skswz = skg ^ ((srow >> 1) & 3);     // inverse swizzle on SOURCE
    const size_t aSrc = (size_t)(row0 + srow) * K + skswz * 8;
    const size_t bSrc = (size_t)(col0 + srow) * K + skswz * 8;

    const int frow = lane & 15;
    const int fkg  = lane >> 4;

    f32x4 acc[2][4] = {};

    for (int k0 = 0; k0 < K; k0 += 32) {
        gload16(AH + aSrc + k0, ldsAH + tid * 8);
        if constexpr (ALO) gload16(AL + aSrc + k0, ldsAL + tid * 8);
        gload16(BH + bSrc + k0, ldsBH + tid * 8);
        gload16(BL + bSrc + k0, ldsBL + tid * 8);
        __syncthreads();   // drains vmcnt before barrier

        bf16x8 a_h[2], a_l[2], b_h[4], b_l[4];
#pragma unroll
        for (int mi = 0; mi < 2; ++mi) {
            int ar  = wm * 32 + mi * 16 + frow;
            int idx = ar * 32 + ((fkg ^ ((ar >> 1) & 3)) * 8);  // swizzled read
            a_h[mi] = *reinterpret_cast<const bf16x8*>(&ldsAH[idx]);
            if constexpr (ALO) a_l[mi] = *reinterpret_cast<const bf16x8*>(&ldsAL[idx]);
        }
#pragma unroll
        for (int ni = 0; ni < 4; ++ni) {
            int bc  = wn * 64 + ni * 16 + frow;
            int idx = bc * 32 + ((fkg ^ ((bc >> 1) & 3)) * 8);
            b_h[ni] = *reinterpret_cast<const bf16x8*>(&ldsBH[idx]);
            b_l[ni] = *reinterpret_cast<const bf16x8*>(&ldsBL[idx]);
        }
#pragma unroll
        for (int mi = 0; mi < 2; ++mi)
#pragma unroll
            for (int ni = 0; ni < 4; ++ni) {
                acc[mi][ni] = __builtin_amdgcn_mfma_f32_16x16x32_bf16(a_h[mi], b_h[ni], acc[mi][ni], 0, 0, 0);
                acc[mi][ni] = __builtin_amdgcn_mfma_f32_16x16x32_bf16(a_h[mi], b_l[ni], acc[mi][ni], 0, 0, 0);
                if constexpr (ALO)
                    acc[mi][ni] = __builtin_amdgcn_mfma_f32_16x16x32_bf16(a_l[mi], b_h[ni], acc[mi][ni], 0, 0, 0);
            }
        __syncthreads();
    }

    // epilogue: D row=(lane>>4)*4+r, col=lane&15 within each 16x16 fragment
#pragma unroll
    for (int mi = 0; mi < 2; ++mi) {
        int rbase = row0 + wm * 32 + mi * 16 + (lane >> 4) * 4;
#pragma unroll
        for (int ni = 0; ni < 4; ++ni) {
            int col = col0 + wn * 64 + ni * 16 + (lane & 15);
            float b = BIAS ? bias[col] : 0.f;
#pragma unroll
            for (int r = 0; r < 4; ++r) {
                int row = rbase + r;
                if (row < NN) C[(size_t)row * NCOLS + col] = acc[mi][ni][r] + b;
            }
        }
    }
}

extern "C" void kernel_launch(void* const* d_in, const int* in_sizes, int n_in,
                              void* d_out, int out_size, void* d_ws, size_t ws_size,
                              hipStream_t stream) {
    const float* feat  = (const float*)d_in[0];
    const int*   src   = (const int*)d_in[1];
    const int*   dst   = (const int*)d_in[2];
    const float* W0    = (const float*)d_in[3];
    const float* W1    = (const float*)d_in[4];
    const float* Wp1   = (const float*)d_in[5];
    const float* bp1   = (const float*)d_in[6];
    const float* gamma = (const float*)d_in[7];
    const float* beta  = (const float*)d_in[8];
    const float* Wp2   = (const float*)d_in[9];
    const float* bp2   = (const float*)d_in[10];
    float* out = (float*)d_out;

    char* wsb = (char*)d_ws;
    // word-offset layout (4B units)
    float* dinv   = (float*)(wsb + 4ull * 0);
    int*   cnt    = (int*)  (wsb + 4ull * 50048);
    int*   rowoff = (int*)  (wsb + 4ull * 100096);
    int*   cursor = (int*)  (wsb + 4ull * 150144);
    int*   bsum   = (int*)  (wsb + 4ull * 200192);
    int*   boff   = (int*)  (wsb + 4ull * 200448);
    int*   eidx   = (int*)  (wsb + 4ull * 200704);
    float* stats  = (float*)(wsb + 4ull * 1000704);
    float* bnscl  = (float*)(wsb + 4ull * 1001216);
    float* bnshf  = (float*)(wsb + 4ull * 1001472);
    // featH [NNP][512] u16  (region reused for Z [NN][256] f32 after GEMM1)
    unsigned short* featH = (unsigned short*)(wsb + 4ull * 1001728);
    float*          Z     = (float*)         (wsb + 4ull * 1001728);
    float* H0 = (float*)(wsb + 4ull * 13814016);            // [NNP][128] f32 (H0, then H2)
    // H1 hi/lo [NNP][128] u16 each (region reused for H3 hi/lo, then ZbnH [NNP][256] u16)
    unsigned short* H1H  = (unsigned short*)(wsb + 4ull * 20220160);
    unsigned short* H1L  = H1H + (size_t)NNP * 128;
    unsigned short* ZbnH = H1H;
    unsigned short* W0tH  = (unsigned short*)(wsb + 4ull * 26626304);
    unsigned short* W0tL  = W0tH + 65536;
    unsigned short* W1tH  = W0tL + 65536;
    unsigned short* W1tL  = W1tH + 16384;
    unsigned short* Wp1tH = W1tL + 16384;
    unsigned short* Wp1tL = Wp1tH + 32768;
    unsigned short* Wp2tH = Wp1tL + 32768;
    unsigned short* Wp2tL = Wp2tH + 32768;

    const int GX = NNP / 128;  // 391

    // ---- CSR build ----
    hipMemsetAsync(cnt, 0, NN * sizeof(int), stream);
    hipMemsetAsync(cursor, 0, NN * sizeof(int), stream);
    k_count<<<(NE + 255) / 256, 256, 0, stream>>>(dst, cnt);
    k_dinv<<<(NN + 255) / 256, 256, 0, stream>>>(cnt, dinv);
    k_bsum<<<NB, 256, 0, stream>>>(cnt, bsum);
    k_scan_bsum<<<1, 256, 0, stream>>>(bsum, boff);
    k_scan_block<<<NB, 256, 0, stream>>>(cnt, boff, rowoff);
    k_fill<<<(NE + 255) / 256, 256, 0, stream>>>(src, dst, rowoff, cursor, eidx);

    // ---- operand conversions ----
    k_feat_bf16<<<(NNP * 128 + 255) / 256, 256, 0, stream>>>(feat, featH);
    k_wsplit<<<(512 * 128 + 255) / 256, 256, 0, stream>>>(W0, W0tH, W0tL, 512, 128);
    k_wsplit<<<(128 * 128 + 255) / 256, 256, 0, stream>>>(W1, W1tH, W1tL, 128, 128);
    k_wsplit<<<(128 * 256 + 255) / 256, 256, 0, stream>>>(Wp1, Wp1tH, Wp1tL, 128, 256);
    k_wsplit<<<(256 * 128 + 255) / 256, 256, 0, stream>>>(Wp2, Wp2tH, Wp2tL, 256, 128);

    // H0 = feat @ W0   (A single-bf16, B split: 2-pass)
    k_mfma<512, 128, false, false><<<dim3(GX, 1), 512, 0, stream>>>(
        featH, nullptr, W0tH, W0tL, nullptr, H0);

    // low_conv #1 -> H1 (hi/lo)
    k_gather_split<<<NNP / 4, 256, 0, stream>>>(H0, dinv, rowoff, cnt, eidx, H1H, H1L);

    // H2 = H1 @ W1   (A split: 3-pass) -> H0 region
    k_mfma<128, 128, false, true><<<dim3(GX, 1), 512, 0, stream>>>(
        H1H, H1L, W1tH, W1tL, nullptr, H0);

    // low_conv #2 -> H3 (hi/lo, same region as H1)
    k_gather_split<<<NNP / 4, 256, 0, stream>>>(H0, dinv, rowoff, cnt, eidx, H1H, H1L);

    // Z = H3 @ Wp1 + bp1   [NN,256]
    k_mfma<128, 256, true, true><<<dim3(GX, 2), 512, 0, stream>>>(
        H1H, H1L, Wp1tH, Wp1tL, bp1, Z);

    // BN stats -> scale/shift
    hipMemsetAsync(stats, 0, 512 * sizeof(float), stream);
    k_colstats<<<500, 256, 0, stream>>>(Z, stats);
    k_bnprep<<<1, 256, 0, stream>>>(stats, gamma, beta, bnscl, bnshf);

    // Zbn = bf16(relu(BN(Z)))  (overwrites H3 region)
    k_bnbf16<<<(NNP * 64 + 255) / 256, 256, 0, stream>>>(Z, bnscl, bnshf, ZbnH);

    // out = Zbn @ Wp2 + bp2   (A single-bf16, B split: 2-pass)
    k_mfma<256, 128, true, false><<<dim3(GX, 1), 512, 0, stream>>>(
        ZbnH, nullptr, Wp2tH, Wp2tL, bp2, out);
}

// Round 4
// 338.610 us; speedup vs baseline: 9.0538x; 1.2927x over previous
//
#include <hip/hip_runtime.h>
#include <math.h>

constexpr int NN  = 50000;
constexpr int NE  = 800000;
constexpr int NNP = 50048;             // padded rows = 391 * 128
constexpr int NB  = (NN + 255) / 256;  // scan blocks

typedef __bf16 bf16x8 __attribute__((ext_vector_type(8)));
typedef float  f32x4  __attribute__((ext_vector_type(4)));
typedef __attribute__((address_space(1))) unsigned int as1_uint;
typedef __attribute__((address_space(3))) unsigned int as3_uint;

__device__ __forceinline__ unsigned short f2bf(float x) {  // RNE fp32->bf16 bits
    unsigned int u = __float_as_uint(x);
    return (unsigned short)((u + 0x7FFFu + ((u >> 16) & 1u)) >> 16);
}
__device__ __forceinline__ float bf2f(unsigned short h) {
    return __uint_as_float(((unsigned int)h) << 16);
}

__device__ __forceinline__ void gload16(const unsigned short* g, unsigned short* l) {
    __builtin_amdgcn_global_load_lds((const as1_uint*)(unsigned long long)g,
                                     (as3_uint*)(unsigned long long)l, 16, 0, 0);
}

// ---------------- CSR build ----------------
__global__ void k_count(const int* __restrict__ dst, int* __restrict__ cnt) {
    int i = blockIdx.x * blockDim.x + threadIdx.x;
    if (i < NE) atomicAdd(&cnt[dst[i]], 1);
}

__global__ void k_dinv(const int* __restrict__ cnt, float* __restrict__ dinv) {
    int i = blockIdx.x * blockDim.x + threadIdx.x;
    if (i < NN) dinv[i] = rsqrtf(fmaxf((float)cnt[i], 1.0f));
}

__global__ void k_bsum(const int* __restrict__ cnt, int* __restrict__ bsum) {
    int i = blockIdx.x * 256 + threadIdx.x;
    int v = (i < NN) ? cnt[i] : 0;
#pragma unroll
    for (int off = 32; off; off >>= 1) v += __shfl_down(v, off, 64);
    __shared__ int tmp[4];
    if ((threadIdx.x & 63) == 0) tmp[threadIdx.x >> 6] = v;
    __syncthreads();
    if (threadIdx.x == 0) bsum[blockIdx.x] = tmp[0] + tmp[1] + tmp[2] + tmp[3];
}

__global__ void k_scan_bsum(const int* __restrict__ bsum, int* __restrict__ boff) {
    __shared__ int s[256];
    int t = threadIdx.x;
    int v = (t < NB) ? bsum[t] : 0;
    s[t] = v;
    __syncthreads();
    for (int off = 1; off < 256; off <<= 1) {
        int u = (t >= off) ? s[t - off] : 0;
        __syncthreads();
        s[t] += u;
        __syncthreads();
    }
    if (t < NB) boff[t] = s[t] - v;
}

__global__ void k_scan_block(const int* __restrict__ cnt, const int* __restrict__ boff,
                             int* __restrict__ rowoff) {
    __shared__ int s[256];
    int t = threadIdx.x;
    int i = blockIdx.x * 256 + t;
    int v = (i < NN) ? cnt[i] : 0;
    s[t] = v;
    __syncthreads();
    for (int off = 1; off < 256; off <<= 1) {
        int u = (t >= off) ? s[t - off] : 0;
        __syncthreads();
        s[t] += u;
        __syncthreads();
    }
    if (i < NN) rowoff[i] = boff[blockIdx.x] + s[t] - v;
}

__global__ void k_fill(const int* __restrict__ src, const int* __restrict__ dst,
                       const int* __restrict__ rowoff, int* __restrict__ cursor,
                       int* __restrict__ eidx) {
    int e = blockIdx.x * blockDim.x + threadIdx.x;
    if (e < NE) {
        int d = dst[e];
        int p = atomicAdd(&cursor[d], 1);
        eidx[rowoff[d] + p] = src[e];
    }
}

// ---------------- fused low_conv gather, bf16 hi/lo in -> hi/lo out ----------------
// neighbors read HI only (half traffic); self reads hi+lo (near-exact)
__global__ __launch_bounds__(256) void k_gather_bf(
    const unsigned short* __restrict__ HH, const unsigned short* __restrict__ HL,
    const float* __restrict__ dinv, const int* __restrict__ rowoff,
    const int* __restrict__ cnt, const int* __restrict__ eidx,
    unsigned short* __restrict__ OH, unsigned short* __restrict__ OL)
{
    int node = blockIdx.x * 4 + (threadIdx.x >> 6);
    int lane = threadIdx.x & 63;
    if (node >= NNP) return;
    size_t o = (size_t)node * 128 + lane * 2;
    if (node >= NN) {  // zero pad rows
        *reinterpret_cast<ushort2*>(&OH[o]) = make_ushort2(0, 0);
        *reinterpret_cast<ushort2*>(&OL[o]) = make_ushort2(0, 0);
        return;
    }
    int beg = rowoff[node];
    int n = cnt[node];
    int c2 = lane * 2;
    float ax = 0.f, ay = 0.f;
    int j = 0;
    for (; j + 2 <= n; j += 2) {  // unroll x2 for ILP
        int s0 = eidx[beg + j], s1 = eidx[beg + j + 1];
        float d0 = dinv[s0], d1 = dinv[s1];
        ushort2 v0 = *reinterpret_cast<const ushort2*>(&HH[(size_t)s0 * 128 + c2]);
        ushort2 v1 = *reinterpret_cast<const ushort2*>(&HH[(size_t)s1 * 128 + c2]);
        ax = fmaf(bf2f(v0.x), d0, ax);
        ay = fmaf(bf2f(v0.y), d0, ay);
        ax = fmaf(bf2f(v1.x), d1, ax);
        ay = fmaf(bf2f(v1.y), d1, ay);
    }
    if (j < n) {
        int s0 = eidx[beg + j];
        float d0 = dinv[s0];
        ushort2 v0 = *reinterpret_cast<const ushort2*>(&HH[(size_t)s0 * 128 + c2]);
        ax = fmaf(bf2f(v0.x), d0, ax);
        ay = fmaf(bf2f(v0.y), d0, ay);
    }
    float d = dinv[node];
    ushort2 sh = *reinterpret_cast<const ushort2*>(&HH[o]);
    ushort2 sl = *reinterpret_cast<const ushort2*>(&HL[o]);
    float hx = fmaf(ax, d, bf2f(sh.x) + bf2f(sl.x));
    float hy = fmaf(ay, d, bf2f(sh.y) + bf2f(sl.y));
    ushort2 hv, lv;
    hv.x = f2bf(hx); lv.x = f2bf(hx - bf2f(hv.x));
    hv.y = f2bf(hy); lv.y = f2bf(hy - bf2f(hv.y));
    *reinterpret_cast<ushort2*>(&OH[o]) = hv;
    *reinterpret_cast<ushort2*>(&OL[o]) = lv;
}

// ---------------- small fp32 GEMM on weights: W1p[128][256] = W1[128][128] @ Wp1[128][256] ----
__global__ void k_mm128(const float* __restrict__ W1, const float* __restrict__ Wp1,
                        float* __restrict__ W1p) {
    int i = blockIdx.x;    // 128
    int j = threadIdx.x;   // 256
    float s = 0.f;
    for (int k = 0; k < 128; ++k) s = fmaf(W1[i * 128 + k], Wp1[k * 256 + j], s);
    W1p[i * 256 + j] = s;
}

// ---------------- weight transpose + hi/lo split: W[K][N] -> Wt[N][K] ----------------
__global__ void k_wsplit(const float* __restrict__ W, unsigned short* __restrict__ th,
                         unsigned short* __restrict__ tl, int K, int N) {
    int idx = blockIdx.x * blockDim.x + threadIdx.x;
    if (idx < K * N) {
        int k = idx / N, n = idx - k * N;
        float a = W[idx];
        unsigned short hi = f2bf(a);
        float lo = a - bf2f(hi);
        th[(size_t)n * K + k] = hi;
        tl[(size_t)n * K + k] = f2bf(lo);
    }
}

// ---------------- BN stats / prep / apply ----------------
__global__ void k_colstats(const float* __restrict__ Z, float* __restrict__ stats) {
    int c = threadIdx.x;
    int rows_per_block = (NN + gridDim.x - 1) / gridDim.x;
    int r0 = blockIdx.x * rows_per_block;
    int r1 = min(r0 + rows_per_block, NN);
    float s = 0.f, s2 = 0.f;
    for (int r = r0; r < r1; ++r) {
        float z = Z[(size_t)r * 256 + c];
        s += z;
        s2 = fmaf(z, z, s2);
    }
    atomicAdd(&stats[c], s);
    atomicAdd(&stats[256 + c], s2);
}

__global__ void k_bnprep(const float* __restrict__ stats, const float* __restrict__ gamma,
                         const float* __restrict__ beta, float* __restrict__ scale,
                         float* __restrict__ shift) {
    int c = threadIdx.x;
    float mu  = stats[c] * (1.0f / NN);
    float var = stats[256 + c] * (1.0f / NN) - mu * mu;
    float s = gamma[c] * rsqrtf(var + 1e-5f);
    scale[c] = s;
    shift[c] = beta[c] - mu * s;
}

__global__ void k_bnbf16(const float* __restrict__ Z, const float* __restrict__ scale,
                         const float* __restrict__ shift, unsigned short* __restrict__ OH) {
    int idx = blockIdx.x * blockDim.x + threadIdx.x;  // float4 over [NNP][256]
    if (idx >= NNP * 64) return;
    int row = idx >> 6;
    int c4 = (idx & 63) * 4;
    ushort4 o;
    if (row < NN) {
        float4 z = reinterpret_cast<const float4*>(Z)[idx];
        float v0 = fmaxf(fmaf(z.x, scale[c4 + 0], shift[c4 + 0]), 0.f);
        float v1 = fmaxf(fmaf(z.y, scale[c4 + 1], shift[c4 + 1]), 0.f);
        float v2 = fmaxf(fmaf(z.z, scale[c4 + 2], shift[c4 + 2]), 0.f);
        float v3 = fmaxf(fmaf(z.w, scale[c4 + 3], shift[c4 + 3]), 0.f);
        o = make_ushort4(f2bf(v0), f2bf(v1), f2bf(v2), f2bf(v3));
    } else o = make_ushort4(0, 0, 0, 0);
    reinterpret_cast<ushort4*>(OH)[idx] = o;
}

// ---------------- split-precision MFMA GEMM ----------------
// A: [NNP][K] (bf16 hi/lo, or fp32 when AF32), Bt: [NCOLS][K] bf16 hi/lo.
// 128x128 tile, BK=32, 8 waves. XOR swizzle (kgroup ^ (row>>1)&3); gload path uses
// inverse-swizzled SOURCE + linear dest; AF32 reg-stages to the same swizzled layout.
// OSPLIT: emit bf16 hi/lo outputs instead of fp32.
template <int K, int NCOLS, bool BIAS, bool ALO, bool AF32, bool OSPLIT>
__global__ __launch_bounds__(512) void k_mfma(
    const unsigned short* __restrict__ AH, const unsigned short* __restrict__ AL,
    const float* __restrict__ Af,
    const unsigned short* __restrict__ BH, const unsigned short* __restrict__ BL,
    const float* __restrict__ bias, float* __restrict__ C,
    unsigned short* __restrict__ OHs, unsigned short* __restrict__ OLs)
{
    __shared__ __align__(16) unsigned short lds[4 * 4096];
    unsigned short* ldsAH = lds;
    unsigned short* ldsAL = lds + 4096;
    unsigned short* ldsBH = lds + 8192;
    unsigned short* ldsBL = lds + 12288;

    const int tid  = threadIdx.x;
    const int lane = tid & 63;
    const int wid  = tid >> 6;
    const int wm   = wid >> 1;
    const int wn   = wid & 1;
    const int row0 = blockIdx.x * 128;
    const int col0 = blockIdx.y * 128;

    const int srow  = tid >> 2;
    const int skg   = tid & 3;
    const int skswz = skg ^ ((srow >> 1) & 3);  // inverse swizzle on SOURCE
    const size_t aSrc = (size_t)(row0 + srow) * K + skswz * 8;
    const size_t bSrc = (size_t)(col0 + srow) * K + skswz * 8;

    const int frow = lane & 15;
    const int fkg  = lane >> 4;

    f32x4 acc[2][4] = {};

    for (int k0 = 0; k0 < K; k0 += 32) {
        if constexpr (AF32) {
            // reg-stage fp32 -> bf16 into same swizzled LDS layout
            float4 f0, f1;
            if (row0 + srow < NN) {
                const float* ap = Af + aSrc + k0;
                f0 = *reinterpret_cast<const float4*>(ap);
                f1 = *reinterpret_cast<const float4*>(ap + 4);
            } else {
                f0 = make_float4(0.f, 0.f, 0.f, 0.f);
                f1 = f0;
            }
            uint4 w;
            w.x = (unsigned)f2bf(f0.x) | ((unsigned)f2bf(f0.y) << 16);
            w.y = (unsigned)f2bf(f0.z) | ((unsigned)f2bf(f0.w) << 16);
            w.z = (unsigned)f2bf(f1.x) | ((unsigned)f2bf(f1.y) << 16);
            w.w = (unsigned)f2bf(f1.z) | ((unsigned)f2bf(f1.w) << 16);
            *reinterpret_cast<uint4*>(&ldsAH[tid * 8]) = w;
        } else {
            gload16(AH + aSrc + k0, ldsAH + tid * 8);
            if constexpr (ALO) gload16(AL + aSrc + k0, ldsAL + tid * 8);
        }
        gload16(BH + bSrc + k0, ldsBH + tid * 8);
        gload16(BL + bSrc + k0, ldsBL + tid * 8);
        __syncthreads();

        bf16x8 a_h[2], a_l[2], b_h[4], b_l[4];
#pragma unroll
        for (int mi = 0; mi < 2; ++mi) {
            int ar  = wm * 32 + mi * 16 + frow;
            int idx = ar * 32 + ((fkg ^ ((ar >> 1) & 3)) * 8);
            a_h[mi] = *reinterpret_cast<const bf16x8*>(&ldsAH[idx]);
            if constexpr (ALO) a_l[mi] = *reinterpret_cast<const bf16x8*>(&ldsAL[idx]);
        }
#pragma unroll
        for (int ni = 0; ni < 4; ++ni) {
            int bc  = wn * 64 + ni * 16 + frow;
            int idx = bc * 32 + ((fkg ^ ((bc >> 1) & 3)) * 8);
            b_h[ni] = *reinterpret_cast<const bf16x8*>(&ldsBH[idx]);
            b_l[ni] = *reinterpret_cast<const bf16x8*>(&ldsBL[idx]);
        }
#pragma unroll
        for (int mi = 0; mi < 2; ++mi)
#pragma unroll
            for (int ni = 0; ni < 4; ++ni) {
                acc[mi][ni] = __builtin_amdgcn_mfma_f32_16x16x32_bf16(a_h[mi], b_h[ni], acc[mi][ni], 0, 0, 0);
                acc[mi][ni] = __builtin_amdgcn_mfma_f32_16x16x32_bf16(a_h[mi], b_l[ni], acc[mi][ni], 0, 0, 0);
                if constexpr (ALO)
                    acc[mi][ni] = __builtin_amdgcn_mfma_f32_16x16x32_bf16(a_l[mi], b_h[ni], acc[mi][ni], 0, 0, 0);
            }
        __syncthreads();
    }

#pragma unroll
    for (int mi = 0; mi < 2; ++mi) {
        int rbase = row0 + wm * 32 + mi * 16 + (lane >> 4) * 4;
#pragma unroll
        for (int ni = 0; ni < 4; ++ni) {
            int col = col0 + wn * 64 + ni * 16 + (lane & 15);
            float b = BIAS ? bias[col] : 0.f;
#pragma unroll
            for (int r = 0; r < 4; ++r) {
                int row = rbase + r;
                if (row < NN) {
                    float v = acc[mi][ni][r] + b;
                    if constexpr (OSPLIT) {
                        unsigned short hi = f2bf(v);
                        OHs[(size_t)row * NCOLS + col] = hi;
                        OLs[(size_t)row * NCOLS + col] = f2bf(v - bf2f(hi));
                    } else {
                        C[(size_t)row * NCOLS + col] = v;
                    }
                }
            }
        }
    }
}

extern "C" void kernel_launch(void* const* d_in, const int* in_sizes, int n_in,
                              void* d_out, int out_size, void* d_ws, size_t ws_size,
                              hipStream_t stream) {
    const float* feat  = (const float*)d_in[0];
    const int*   src   = (const int*)d_in[1];
    const int*   dst   = (const int*)d_in[2];
    const float* W0    = (const float*)d_in[3];
    const float* W1    = (const float*)d_in[4];
    const float* Wp1   = (const float*)d_in[5];
    const float* bp1   = (const float*)d_in[6];
    const float* gamma = (const float*)d_in[7];
    const float* beta  = (const float*)d_in[8];
    const float* Wp2   = (const float*)d_in[9];
    const float* bp2   = (const float*)d_in[10];
    float* out = (float*)d_out;

    char* wsb = (char*)d_ws;
    float* dinv   = (float*)(wsb + 4ull * 0);
    int*   cnt    = (int*)  (wsb + 4ull * 50048);
    int*   rowoff = (int*)  (wsb + 4ull * 100096);
    int*   cursor = (int*)  (wsb + 4ull * 150144);
    int*   bsum   = (int*)  (wsb + 4ull * 200192);
    int*   boff   = (int*)  (wsb + 4ull * 200448);
    int*   eidx   = (int*)  (wsb + 4ull * 200704);
    float* stats  = (float*)(wsb + 4ull * 1000704);
    float* bnscl  = (float*)(wsb + 4ull * 1001216);
    float* bnshf  = (float*)(wsb + 4ull * 1001472);
    float* W1p    = (float*)(wsb + 4ull * 1001728);          // [128][256] fp32
    unsigned short* W0tH  = (unsigned short*)(wsb + 4ull * 1034496);
    unsigned short* W0tL  = W0tH + 65536;
    unsigned short* W1ptH = W0tL + 65536;
    unsigned short* W1ptL = W1ptH + 32768;
    unsigned short* Wp2tH = W1ptL + 32768;
    unsigned short* Wp2tL = Wp2tH + 32768;                   // ends word 1165568
    unsigned short* H0H = (unsigned short*)(wsb + 4ull * 1165568);   // [NNP][128] u16
    unsigned short* H0L = (unsigned short*)(wsb + 4ull * 4368640);
    unsigned short* h1H = (unsigned short*)(wsb + 4ull * 7571712);
    unsigned short* h1L = (unsigned short*)(wsb + 4ull * 10774784);
    unsigned short* h2H = H0H;   // reuse after H0 consumed
    unsigned short* h2L = H0L;
    unsigned short* ZbnH = h1H;  // reuse after h1 consumed ([NNP][256] u16 = same bytes)
    float* Z = (float*)(wsb + 4ull * 13977856);              // [NN][256] fp32

    const int GX = NNP / 128;  // 391

    // ---- CSR build ----
    hipMemsetAsync(cnt, 0, NN * sizeof(int), stream);
    hipMemsetAsync(cursor, 0, NN * sizeof(int), stream);
    k_count<<<(NE + 255) / 256, 256, 0, stream>>>(dst, cnt);
    k_dinv<<<(NN + 255) / 256, 256, 0, stream>>>(cnt, dinv);
    k_bsum<<<NB, 256, 0, stream>>>(cnt, bsum);
    k_scan_bsum<<<1, 256, 0, stream>>>(bsum, boff);
    k_scan_block<<<NB, 256, 0, stream>>>(cnt, boff, rowoff);
    k_fill<<<(NE + 255) / 256, 256, 0, stream>>>(src, dst, rowoff, cursor, eidx);

    // ---- weight prep ----
    k_wsplit<<<(512 * 128 + 255) / 256, 256, 0, stream>>>(W0, W0tH, W0tL, 512, 128);
    k_mm128<<<128, 256, 0, stream>>>(W1, Wp1, W1p);                    // W1p = W1 @ Wp1
    k_wsplit<<<(128 * 256 + 255) / 256, 256, 0, stream>>>(W1p, W1ptH, W1ptL, 128, 256);
    k_wsplit<<<(256 * 128 + 255) / 256, 256, 0, stream>>>(Wp2, Wp2tH, Wp2tL, 256, 128);

    // H0 = feat @ W0  (A fp32 reg-staged, B split 2-pass, output hi/lo)
    k_mfma<512, 128, false, false, true, true><<<dim3(GX, 1), 512, 0, stream>>>(
        nullptr, nullptr, feat, W0tH, W0tL, nullptr, nullptr, H0H, H0L);

    // h1 = conv(H0); h2 = conv(h1)   [conv commutes with right-mult by W]
    k_gather_bf<<<NNP / 4, 256, 0, stream>>>(H0H, H0L, dinv, rowoff, cnt, eidx, h1H, h1L);
    k_gather_bf<<<NNP / 4, 256, 0, stream>>>(h1H, h1L, dinv, rowoff, cnt, eidx, h2H, h2L);

    // Z = h2 @ (W1@Wp1) + bp1   [NN,256]  (A split 3-pass)
    k_mfma<128, 256, true, true, false, false><<<dim3(GX, 2), 512, 0, stream>>>(
        h2H, h2L, nullptr, W1ptH, W1ptL, bp1, Z, nullptr, nullptr);

    // BN stats -> scale/shift
    hipMemsetAsync(stats, 0, 512 * sizeof(float), stream);
    k_colstats<<<500, 256, 0, stream>>>(Z, stats);
    k_bnprep<<<1, 256, 0, stream>>>(stats, gamma, beta, bnscl, bnshf);

    // Zbn = bf16(relu(BN(Z)))
    k_bnbf16<<<(NNP * 64 + 255) / 256, 256, 0, stream>>>(Z, bnscl, bnshf, ZbnH);

    // out = Zbn @ Wp2 + bp2  (A single bf16, B split 2-pass)
    k_mfma<256, 128, true, false, false, false><<<dim3(GX, 1), 512, 0, stream>>>(
        ZbnH, nullptr, nullptr, Wp2tH, Wp2tL, bp2, out, nullptr, nullptr);
}